// Round 8
// baseline (251.445 us; speedup 1.0000x reference)
//
#include <hip/hip_runtime.h>
#include <math.h>

constexpr int B = 4;
constexpr int N = 8192;
constexpr int KNN = 8;
constexpr int CHUNK = 64;              // candidates per chunk
constexpr int NCHUNKS = N / CHUNK;     // 128
constexpr int NGROUPS = NCHUNKS / 4;   // 32 groups of 4 chunks
constexpr int BINS = 512;              // 8x8x8 Morton cells
constexpr int WQC = 4;                 // query-chunk waves per block

__device__ __forceinline__ int morton9(int x, int y, int z) {
  int c = 0;
#pragma unroll
  for (int b = 0; b < 3; ++b)
    c |= (((x >> b) & 1) << (3 * b + 2)) | (((y >> b) & 1) << (3 * b + 1)) |
         (((z >> b) & 1) << (3 * b + 0));
  return c;
}

// One block per (array, batch): packs float4 (x,y,z,|p|^2/2), counting-sorts
// the 8192 points by Morton cell (wave-shfl scan, 3 barriers), writes sorted
// copy and per-chunk interleaved AABBs (lo,hi). Exact: permutation only.
__global__ __launch_bounds__(1024) void prep_sort_kernel(
    const float* __restrict__ src, const float* __restrict__ tgt,
    const float* __restrict__ flow, float4* __restrict__ sorted,
    float4* __restrict__ aabb, float* __restrict__ out) {
  int arr = blockIdx.x >> 2;  // 0 = pred(src+flow), 1 = tgt
  int batch = blockIdx.x & 3;
  int t = threadIdx.x;
  if (blockIdx.x == 0 && t == 0) out[0] = 0.0f;

  __shared__ int hist[BINS], cnt[BINS];
  __shared__ int wsum[8], wpre[8];

  const float* base = (arr == 0 ? src : tgt) + batch * N * 3;
  const float* fbase = flow + batch * N * 3;

  float4 P[8];
  int code[8];
#pragma unroll
  for (int k = 0; k < 8; ++k) {
    int i = t + k * 1024;
    float x = base[3 * i], y = base[3 * i + 1], z = base[3 * i + 2];
    if (arr == 0) { x += fbase[3 * i]; y += fbase[3 * i + 1]; z += fbase[3 * i + 2]; }
    P[k] = make_float4(x, y, z, 0.5f * (x * x + y * y + z * z));
    int cx = min(max((int)floorf(x + 4.0f), 0), 7);
    int cy = min(max((int)floorf(y + 4.0f), 0), 7);
    int cz = min(max((int)floorf(z + 4.0f), 0), 7);
    code[k] = morton9(cx, cy, cz);
  }
  if (t < BINS) hist[t] = 0;
  __syncthreads();
#pragma unroll
  for (int k = 0; k < 8; ++k) atomicAdd(&hist[code[k]], 1);
  __syncthreads();

  // exclusive scan of hist via wave-shfl (512 bins = 8 waves x 64 lanes)
  int v = (t < BINS) ? hist[t] : 0;
#pragma unroll
  for (int off = 1; off < 64; off <<= 1) {
    int n = __shfl_up(v, off);
    if ((t & 63) >= off) v += n;
  }
  if (t < BINS && (t & 63) == 63) wsum[t >> 6] = v;
  __syncthreads();
  if (t < 8) {
    int sv = wsum[t];
#pragma unroll
    for (int off = 1; off < 8; off <<= 1) {
      int n = __shfl_up(sv, off);
      if (t >= off) sv += n;
    }
    wpre[t] = sv - wsum[t];  // exclusive prefix of wave sums
  }
  __syncthreads();
  if (t < BINS) cnt[t] = v - hist[t] + wpre[t >> 6];
  __syncthreads();

  float4* sout = sorted + (arr * 4 + batch) * N;
#pragma unroll
  for (int k = 0; k < 8; ++k) {
    int dest = atomicAdd(&cnt[code[k]], 1);
    sout[dest] = P[k];
  }
  __threadfence_block();
  __syncthreads();

  // per-chunk AABB: 8 threads per chunk x 8 points each, shfl-reduce
  int ch = t >> 3, sub = t & 7;
  float lx = INFINITY, ly = INFINITY, lz = INFINITY;
  float hx = -INFINITY, hy = -INFINITY, hz = -INFINITY;
#pragma unroll
  for (int k = 0; k < 8; ++k) {
    float4 p = sout[ch * CHUNK + sub * 8 + k];
    lx = fminf(lx, p.x); ly = fminf(ly, p.y); lz = fminf(lz, p.z);
    hx = fmaxf(hx, p.x); hy = fmaxf(hy, p.y); hz = fmaxf(hz, p.z);
  }
#pragma unroll
  for (int m = 1; m < 8; m <<= 1) {
    lx = fminf(lx, __shfl_xor(lx, m)); ly = fminf(ly, __shfl_xor(ly, m));
    lz = fminf(lz, __shfl_xor(lz, m)); hx = fmaxf(hx, __shfl_xor(hx, m));
    hy = fmaxf(hy, __shfl_xor(hy, m)); hz = fmaxf(hz, __shfl_xor(hz, m));
  }
  if (sub == 0) {
    int ai = ((arr * 4 + batch) * NCHUNKS + ch) * 2;
    aabb[ai + 0] = make_float4(lx, ly, lz, 0.0f);
    aabb[ai + 1] = make_float4(hx, hy, hz, 0.0f);
  }
}

// Insert tv into sorted ascending d[0..7]: d'[0]=min(d0,tv), d'[i]=med3(...).
__device__ __forceinline__ void insert8(float (&d)[KNN], float tv) {
  float n0 = fminf(d[0], tv);
  float n1 = __builtin_amdgcn_fmed3f(d[0], d[1], tv);
  float n2 = __builtin_amdgcn_fmed3f(d[1], d[2], tv);
  float n3 = __builtin_amdgcn_fmed3f(d[2], d[3], tv);
  float n4 = __builtin_amdgcn_fmed3f(d[3], d[4], tv);
  float n5 = __builtin_amdgcn_fmed3f(d[4], d[5], tv);
  float n6 = __builtin_amdgcn_fmed3f(d[5], d[6], tv);
  float n7 = __builtin_amdgcn_fmed3f(d[6], d[7], tv);
  d[0] = n0; d[1] = n1; d[2] = n2; d[3] = n3;
  d[4] = n4; d[5] = n5; d[6] = n6; d[7] = n7;
}

// One WAVE per query chunk (64 queries, one per lane), scanning ALL 128
// candidate chunks with a GLOBAL per-lane threshold (round 7's failure was
// slice-local thresholds). Spiral visit order from the query's own Morton
// position bootstraps r2 to ~true r8 after the first group; remaining AABB
// header tests (prefetched one group ahead) then prune ~95% of chunks.
// No slicing -> no merge, no __syncthreads anywhere.
__global__ __launch_bounds__(256, 4) void chamfer_kernel(
    const float4* __restrict__ sorted, const float4* __restrict__ aabb,
    float* __restrict__ out) {
  int lane = threadIdx.x & 63;
  int wave = threadIdx.x >> 6;
  int qcid = blockIdx.x * WQC + wave;  // [0, 1024)
  int dir = qcid >> 9;                 // 0: pred->tgt, 1: tgt->pred
  int batch = (qcid >> 7) & 3;
  int qc = qcid & 127;
  const float4* __restrict__ qarr = sorted + ((dir == 0 ? 0 : 4) + batch) * N;
  const float4* __restrict__ parr = sorted + ((dir == 0 ? 4 : 0) + batch) * N;
  const float4* __restrict__ ab = aabb + ((dir == 0 ? 4 : 0) + batch) * (2 * NCHUNKS);

  float4 q = qarr[qc * CHUNK + lane];
  float q2 = 2.0f * q.w;
  float nqx = -q.x, nqy = -q.y, nqz = -q.z;

  __shared__ float4 stage[WQC][CHUNK];  // 4 KB, per-wave private

  float d[KNN];
#pragma unroll
  for (int i = 0; i < KNN; ++i) d[i] = INFINITY;

  int g0 = qc >> 2;  // both clouds share the Morton grid -> spatial alignment
  float4 h[8];
  {
    const float4* hp = ab + g0 * 8;
#pragma unroll
    for (int u = 0; u < 8; ++u) h[u] = hp[u];
  }

  for (int s = 0; s < NGROUPS; ++s) {
    float4 hc[8];
#pragma unroll
    for (int u = 0; u < 8; ++u) hc[u] = h[u];
    int off = (s + 1) >> 1;
    int gcur = (g0 + ((s & 1) ? off : -off)) & (NGROUPS - 1);
    if (s + 1 < NGROUPS) {  // prefetch next group's headers
      int off2 = (s + 2) >> 1;
      int gn = (g0 + (((s + 1) & 1) ? off2 : -off2)) & (NGROUPS - 1);
      const float4* hpn = ab + gn * 8;
#pragma unroll
      for (int u = 0; u < 8; ++u) h[u] = hpn[u];
    }
#pragma unroll
    for (int u = 0; u < 4; ++u) {
      float4 lo = hc[2 * u], hi = hc[2 * u + 1];
      float ax = fmaxf(fmaxf(lo.x - q.x, q.x - hi.x), 0.0f);
      float ay = fmaxf(fmaxf(lo.y - q.y, q.y - hi.y), 0.0f);
      float az = fmaxf(fmaxf(lo.z - q.z, q.z - hi.z), 0.0f);
      float d2box = __builtin_fmaf(ax, ax, __builtin_fmaf(ay, ay, az * az));
      float r2 = __builtin_fmaf(2.0f, d[KNN - 1], q2) + 1e-4f;
      if (__ballot(d2box < r2)) {  // wave-uniform
        int j = gcur * 4 + u;
        stage[wave][lane] = parr[j * CHUNK + lane];  // wave-local, no barrier
#pragma unroll 8
        for (int i = 0; i < CHUNK; ++i) {
          float4 p = stage[wave][i];  // broadcast ds_read_b128
          float tv = __builtin_fmaf(nqx, p.x,
                     __builtin_fmaf(nqy, p.y,
                     __builtin_fmaf(nqz, p.z, p.w)));
          insert8(d, tv);
        }
      }
    }
  }

  float s_ = 0.0f;
#pragma unroll
  for (int i = 0; i < KNN; ++i) {
    float d2 = fmaxf(__builtin_fmaf(2.0f, d[i], q2), 0.0f);
    s_ += sqrtf(d2);
  }
  float val = s_ * (1.0f / KNN);
  for (int off = 32; off; off >>= 1) val += __shfl_down(val, off, 64);
  if (lane == 0) atomicAdd(out, val * (1.0f / (B * N)));
}

extern "C" void kernel_launch(void* const* d_in, const int* in_sizes, int n_in,
                              void* d_out, int out_size, void* d_ws, size_t ws_size,
                              hipStream_t stream) {
  const float* src = (const float*)d_in[0];
  const float* tgt = (const float*)d_in[1];
  const float* flow = (const float*)d_in[2];
  float* out = (float*)d_out;
  float4* sorted = (float4*)d_ws;            // 2*4*8192 float4 = 1 MB
  float4* aabb = sorted + 2 * 4 * N;         // 2*4*128*2 float4 = 32 KB

  prep_sort_kernel<<<8, 1024, 0, stream>>>(src, tgt, flow, sorted, aabb, out);
  chamfer_kernel<<<2 * B * NCHUNKS / WQC, 256, 0, stream>>>(sorted, aabb, out);
}

// Round 9
// 201.409 us; speedup vs baseline: 1.2484x; 1.2484x over previous
//
#include <hip/hip_runtime.h>
#include <math.h>

constexpr int B = 4;
constexpr int N = 8192;
constexpr int KNN = 8;
constexpr int CHUNK = 64;              // candidates per chunk
constexpr int NCHUNKS = N / CHUNK;     // 128
constexpr int NGROUPS = NCHUNKS / 4;   // 32 groups of 4 chunks
constexpr int BINS = 512;              // 8x8x8 Morton cells
constexpr int WPB = 4;                 // waves per block (slices per query chunk)
constexpr int GPS = NGROUPS / WPB;     // 8 groups per slice

__device__ __forceinline__ int morton9(int x, int y, int z) {
  int c = 0;
#pragma unroll
  for (int b = 0; b < 3; ++b)
    c |= (((x >> b) & 1) << (3 * b + 2)) | (((y >> b) & 1) << (3 * b + 1)) |
         (((z >> b) & 1) << (3 * b + 0));
  return c;
}

// One block per (array, batch): packs float4 (x,y,z,|p|^2/2), counting-sorts
// the 8192 points by Morton cell (wave-shfl scan), writes sorted copy and
// per-chunk interleaved AABBs (lo,hi). Exact: permutation only.
__global__ __launch_bounds__(1024) void prep_sort_kernel(
    const float* __restrict__ src, const float* __restrict__ tgt,
    const float* __restrict__ flow, float4* __restrict__ sorted,
    float4* __restrict__ aabb, float* __restrict__ out) {
  int arr = blockIdx.x >> 2;  // 0 = pred(src+flow), 1 = tgt
  int batch = blockIdx.x & 3;
  int t = threadIdx.x;
  if (blockIdx.x == 0 && t == 0) out[0] = 0.0f;

  __shared__ int hist[BINS], cnt[BINS];
  __shared__ int wsum[8], wpre[8];

  const float* base = (arr == 0 ? src : tgt) + batch * N * 3;
  const float* fbase = flow + batch * N * 3;

  float4 P[8];
  int code[8];
#pragma unroll
  for (int k = 0; k < 8; ++k) {
    int i = t + k * 1024;
    float x = base[3 * i], y = base[3 * i + 1], z = base[3 * i + 2];
    if (arr == 0) { x += fbase[3 * i]; y += fbase[3 * i + 1]; z += fbase[3 * i + 2]; }
    P[k] = make_float4(x, y, z, 0.5f * (x * x + y * y + z * z));
    int cx = min(max((int)floorf(x + 4.0f), 0), 7);
    int cy = min(max((int)floorf(y + 4.0f), 0), 7);
    int cz = min(max((int)floorf(z + 4.0f), 0), 7);
    code[k] = morton9(cx, cy, cz);
  }
  if (t < BINS) hist[t] = 0;
  __syncthreads();
#pragma unroll
  for (int k = 0; k < 8; ++k) atomicAdd(&hist[code[k]], 1);
  __syncthreads();

  int v = (t < BINS) ? hist[t] : 0;
#pragma unroll
  for (int off = 1; off < 64; off <<= 1) {
    int n = __shfl_up(v, off);
    if ((t & 63) >= off) v += n;
  }
  if (t < BINS && (t & 63) == 63) wsum[t >> 6] = v;
  __syncthreads();
  if (t < 8) {
    int sv = wsum[t];
#pragma unroll
    for (int off = 1; off < 8; off <<= 1) {
      int n = __shfl_up(sv, off);
      if (t >= off) sv += n;
    }
    wpre[t] = sv - wsum[t];
  }
  __syncthreads();
  if (t < BINS) cnt[t] = v - hist[t] + wpre[t >> 6];
  __syncthreads();

  float4* sout = sorted + (arr * 4 + batch) * N;
#pragma unroll
  for (int k = 0; k < 8; ++k) {
    int dest = atomicAdd(&cnt[code[k]], 1);
    sout[dest] = P[k];
  }
  __threadfence_block();
  __syncthreads();

  int ch = t >> 3, sub = t & 7;
  float lx = INFINITY, ly = INFINITY, lz = INFINITY;
  float hx = -INFINITY, hy = -INFINITY, hz = -INFINITY;
#pragma unroll
  for (int k = 0; k < 8; ++k) {
    float4 p = sout[ch * CHUNK + sub * 8 + k];
    lx = fminf(lx, p.x); ly = fminf(ly, p.y); lz = fminf(lz, p.z);
    hx = fmaxf(hx, p.x); hy = fmaxf(hy, p.y); hz = fmaxf(hz, p.z);
  }
#pragma unroll
  for (int m = 1; m < 8; m <<= 1) {
    lx = fminf(lx, __shfl_xor(lx, m)); ly = fminf(ly, __shfl_xor(ly, m));
    lz = fminf(lz, __shfl_xor(lz, m)); hx = fmaxf(hx, __shfl_xor(hx, m));
    hy = fmaxf(hy, __shfl_xor(hy, m)); hz = fmaxf(hz, __shfl_xor(hz, m));
  }
  if (sub == 0) {
    int ai = ((arr * 4 + batch) * NCHUNKS + ch) * 2;
    aabb[ai + 0] = make_float4(lx, ly, lz, 0.0f);
    aabb[ai + 1] = make_float4(hx, hy, hz, 0.0f);
  }
}

// Insert tv into sorted ascending d[0..7]: d'[0]=min(d0,tv), d'[i]=med3(...).
__device__ __forceinline__ void insert8(float (&d)[KNN], float tv) {
  float n0 = fminf(d[0], tv);
  float n1 = __builtin_amdgcn_fmed3f(d[0], d[1], tv);
  float n2 = __builtin_amdgcn_fmed3f(d[1], d[2], tv);
  float n3 = __builtin_amdgcn_fmed3f(d[2], d[3], tv);
  float n4 = __builtin_amdgcn_fmed3f(d[3], d[4], tv);
  float n5 = __builtin_amdgcn_fmed3f(d[4], d[5], tv);
  float n6 = __builtin_amdgcn_fmed3f(d[5], d[6], tv);
  float n7 = __builtin_amdgcn_fmed3f(d[6], d[7], tv);
  d[0] = n0; d[1] = n1; d[2] = n2; d[3] = n3;
  d[4] = n4; d[5] = n5; d[6] = n6; d[7] = n7;
}

// One BLOCK (4 waves) per query chunk. Phase 1 (all waves): process the
// query's own Morton group g0 (4 chunks) -> frozen per-lane bound b >= global
// r8. Phase 2: wave w scans its private 8-group slice, pruning chunks via
// AABB distance vs r2 = 2*min(b, d[7]) + q2 (b-pruned candidates can't be in
// the global top-8; d[7]-pruned can't be in the slice top-8 — merge of slice
// top-8s is exact either way). Owner wave keeps bootstrap d (its slice holds
// g0); others reset to INF so merge has no duplicates. 1024 blocks = 4096
// waves (round 8's failure: 1024 waves, uncorrelated stragglers).
__global__ __launch_bounds__(256, 4) void chamfer_kernel(
    const float4* __restrict__ sorted, const float4* __restrict__ aabb,
    float* __restrict__ out) {
  int lane = threadIdx.x & 63;
  int wave = threadIdx.x >> 6;
  int qcid = blockIdx.x;               // [0, 1024)
  int dir = qcid >> 9;                 // 0: pred->tgt, 1: tgt->pred
  int batch = (qcid >> 7) & 3;
  int qc = qcid & 127;
  const float4* __restrict__ qarr = sorted + ((dir == 0 ? 0 : 4) + batch) * N;
  const float4* __restrict__ parr = sorted + ((dir == 0 ? 4 : 0) + batch) * N;
  const float4* __restrict__ ab = aabb + ((dir == 0 ? 4 : 0) + batch) * (2 * NCHUNKS);

  float4 q = qarr[qc * CHUNK + lane];
  float q2 = 2.0f * q.w;
  float nqx = -q.x, nqy = -q.y, nqz = -q.z;

  __shared__ float4 stage[WPB][CHUNK];           // 4 KB, per-wave private
  __shared__ float part[WPB][CHUNK][KNN + 1];    // 9 KB, merge buffer

  float d[KNN];
#pragma unroll
  for (int i = 0; i < KNN; ++i) d[i] = INFINITY;

  int g0 = qc >> 2;          // query chunk's own candidate group
  int owner = g0 >> 3;       // wave whose slice contains g0

  // Phase 1: bootstrap on group g0 (all 4 chunks), every wave
#pragma unroll
  for (int u = 0; u < 4; ++u) {
    int j = g0 * 4 + u;
    stage[wave][lane] = parr[j * CHUNK + lane];  // wave-private, no barrier
#pragma unroll 8
    for (int i = 0; i < CHUNK; ++i) {
      float4 p = stage[wave][i];
      float tv = __builtin_fmaf(nqx, p.x,
                 __builtin_fmaf(nqy, p.y,
                 __builtin_fmaf(nqz, p.z, p.w)));
      insert8(d, tv);
    }
  }
  float b = d[KNN - 1];  // frozen global bound (rank key units)
  if (wave != owner) {
#pragma unroll
    for (int i = 0; i < KNN; ++i) d[i] = INFINITY;
  }

  // Phase 2: scan private slice with pruning
  for (int gi = 0; gi < GPS; ++gi) {
    int g = wave * GPS + gi;
    if (g == g0) continue;  // owner already has it from bootstrap
    const float4* hp = ab + g * 8;
#pragma unroll
    for (int u = 0; u < 4; ++u) {
      float4 lo = hp[2 * u], hi = hp[2 * u + 1];
      float ax = fmaxf(fmaxf(lo.x - q.x, q.x - hi.x), 0.0f);
      float ay = fmaxf(fmaxf(lo.y - q.y, q.y - hi.y), 0.0f);
      float az = fmaxf(fmaxf(lo.z - q.z, q.z - hi.z), 0.0f);
      float d2box = __builtin_fmaf(ax, ax, __builtin_fmaf(ay, ay, az * az));
      float r2 = __builtin_fmaf(2.0f, fminf(b, d[KNN - 1]), q2) + 1e-4f;
      if (__ballot(d2box < r2)) {
        int j = g * 4 + u;
        stage[wave][lane] = parr[j * CHUNK + lane];
#pragma unroll 8
        for (int i = 0; i < CHUNK; ++i) {
          float4 p = stage[wave][i];
          float tv = __builtin_fmaf(nqx, p.x,
                     __builtin_fmaf(nqy, p.y,
                     __builtin_fmaf(nqz, p.z, p.w)));
          insert8(d, tv);
        }
      }
    }
  }

  // merge 4 waves' top-8 per query
#pragma unroll
  for (int i = 0; i < KNN; ++i) part[wave][lane][i] = d[i];
  __syncthreads();

  if (wave == 0) {
    float m[KNN];
#pragma unroll
    for (int i = 0; i < KNN; ++i) m[i] = part[0][lane][i];
#pragma unroll
    for (int s = 1; s < WPB; ++s)
#pragma unroll
      for (int i = 0; i < KNN; ++i) insert8(m, part[s][lane][i]);
    float s_ = 0.0f;
#pragma unroll
    for (int i = 0; i < KNN; ++i) {
      float d2 = fmaxf(__builtin_fmaf(2.0f, m[i], q2), 0.0f);
      s_ += sqrtf(d2);
    }
    float val = s_ * (1.0f / KNN);
    for (int off = 32; off; off >>= 1) val += __shfl_down(val, off, 64);
    if (lane == 0) atomicAdd(out, val * (1.0f / (B * N)));
  }
}

extern "C" void kernel_launch(void* const* d_in, const int* in_sizes, int n_in,
                              void* d_out, int out_size, void* d_ws, size_t ws_size,
                              hipStream_t stream) {
  const float* src = (const float*)d_in[0];
  const float* tgt = (const float*)d_in[1];
  const float* flow = (const float*)d_in[2];
  float* out = (float*)d_out;
  float4* sorted = (float4*)d_ws;            // 2*4*8192 float4 = 1 MB
  float4* aabb = sorted + 2 * 4 * N;         // 2*4*128*2 float4 = 32 KB

  prep_sort_kernel<<<8, 1024, 0, stream>>>(src, tgt, flow, sorted, aabb, out);
  chamfer_kernel<<<2 * B * NCHUNKS, 256, 0, stream>>>(sorted, aabb, out);
}